// Round 3
// baseline (55.688 us; speedup 1.0000x reference)
//
#include <hip/hip_runtime.h>

// Problem constants (fixed by setup_inputs): lfi [B,A,H,W,C], f_maps [B,H,W,F]
#define BB 4
#define AA 9
#define HH 256
#define WW 256
#define CC 9
#define FF 64
#define WF (WW * FF)   // 16384 floats per h-row of f_maps
#define WF4 (WF / 4)   // 4096 float4 per h-row

// ---------------------------------------------------------------------------
// Stage 1 (fused, disjoint block roles), NCH = h-chunks per batch:
//  blocks [0, BB*NCH):  row-streaming partial column-sums of f_maps.
//    Block (b, ch) reads rows h = ch*R .. ch*R+R-1 fully contiguously
//    (float4, 4KB per wave-instruction), accumulating 16 float4 in registers,
//    then writes one 64KB partial plane partial[b][ch][w*F+f].
//  blocks [BB*NCH, +1024): m[b,h,w] = mean_{a,c} lfi[b,a,h,w,c] via LDS
//    staging: per a, the block float4-loads its contiguous 9216B span
//    (coalesced, each line touched once), then each thread sums 9 LDS floats
//    (stride 9 -> bank-conflict-free).
// ---------------------------------------------------------------------------
template <int NCH>
__global__ __launch_bounds__(256, 2) void k_stage1(const float* __restrict__ fm,
                                                   const float* __restrict__ lfi,
                                                   float* __restrict__ partial,
                                                   float* __restrict__ m) {
    constexpr int R = HH / NCH;  // rows per chunk
    const int t = threadIdx.x;

    if (blockIdx.x < BB * NCH) {
        // ---- hv partial role ----
        const int b = blockIdx.x / NCH;
        const int ch = blockIdx.x % NCH;
        const float4* row = (const float4*)fm + (size_t)(b * HH + ch * R) * WF4;

        float4 acc[16];
#pragma unroll
        for (int k = 0; k < 16; ++k) acc[k] = make_float4(0.f, 0.f, 0.f, 0.f);

        for (int r = 0; r < R; ++r) {
#pragma unroll
            for (int k = 0; k < 16; ++k) {
                float4 v = row[(size_t)r * WF4 + k * 256 + t];
                acc[k].x += v.x; acc[k].y += v.y; acc[k].z += v.z; acc[k].w += v.w;
            }
        }
        float4* pout = (float4*)partial + (size_t)(b * NCH + ch) * WF4;
#pragma unroll
        for (int k = 0; k < 16; ++k) pout[k * 256 + t] = acc[k];
    } else {
        // ---- m role ----
        const int blkm = blockIdx.x - BB * NCH;  // 0..1023
        const int b = blkm >> 8;                 // 256 blocks per batch
        const int hw0 = (blkm & 255) * 256;      // within-b hw start

        __shared__ float lds[256 * CC];          // 9216B
        const size_t astride = (size_t)HH * WW * CC;  // 589824
        const float* base = lfi + (size_t)b * AA * astride + (size_t)hw0 * CC;

        float s = 0.f;
        for (int a = 0; a < AA; ++a) {
            const float4* src = (const float4*)(base + (size_t)a * astride);
            float4* l4 = (float4*)lds;
            l4[t] = src[t];
            l4[t + 256] = src[t + 256];
            if (t < 64) l4[t + 512] = src[t + 512];
            __syncthreads();
            float ps = 0.f;
#pragma unroll
            for (int c = 0; c < CC; ++c) ps += lds[t * CC + c];
            s += ps;
            __syncthreads();
        }
        m[(size_t)blkm * 256 + t] = s * (1.0f / (AA * CC));
    }
}

// ---------------------------------------------------------------------------
// Reduce: hv[b][wf] = (1/H) * sum_ch partial[b][ch][wf]; per-(b,f) max into
// maxbuf via block-local LDS max (over the block's 16 w) + 64 atomicMax.
// Grid: BB*16 blocks of 256 (thread = one float4 of the wf plane).
// ---------------------------------------------------------------------------
template <int NCH>
__global__ __launch_bounds__(256) void k_reduce(const float* __restrict__ partial,
                                                float* __restrict__ hv,
                                                int* __restrict__ maxbuf) {
    const int t = threadIdx.x;
    const int b = blockIdx.x >> 4;  // 16 blocks per batch
    const int i = blockIdx.x & 15;
    const int wf4 = i * 256 + t;    // 0..4095

    const float4* p4 = (const float4*)partial + (size_t)b * NCH * WF4 + wf4;
    float4 s = make_float4(0.f, 0.f, 0.f, 0.f);
#pragma unroll
    for (int ch = 0; ch < NCH; ++ch) {
        float4 v = p4[(size_t)ch * WF4];
        s.x += v.x; s.y += v.y; s.z += v.z; s.w += v.w;
    }
    s.x *= (1.0f / HH); s.y *= (1.0f / HH); s.z *= (1.0f / HH); s.w *= (1.0f / HH);
    ((float4*)hv)[(size_t)b * WF4 + wf4] = s;

    // block spans w = i*16 + (t>>4), f = (t&15)*4 .. +3
    __shared__ float lmax[16][FF];
    const int wl = t >> 4, f4 = t & 15;
    lmax[wl][f4 * 4 + 0] = s.x;
    lmax[wl][f4 * 4 + 1] = s.y;
    lmax[wl][f4 * 4 + 2] = s.z;
    lmax[wl][f4 * 4 + 3] = s.w;
    __syncthreads();
    if (t < FF) {
        float mx = lmax[0][t];
#pragma unroll
        for (int j = 1; j < 16; ++j) mx = fmaxf(mx, lmax[j][t]);
        atomicMax(maxbuf + b * FF + t, __float_as_int(mx));  // positive floats
    }
}

// ---------------------------------------------------------------------------
// Stage 2: out[b,h,w,f] = m[b,h,w] * hv[b,h,f] / max[b,f]
// ---------------------------------------------------------------------------
__global__ __launch_bounds__(256) void k_out(const float* __restrict__ m,
                                             const float* __restrict__ hv,
                                             const int* __restrict__ maxbuf,
                                             float4* __restrict__ out) {
    const int idx = blockIdx.x * 256 + threadIdx.x;  // over B*H*W*F/4
    const int f4 = idx & 15;                         // FF/4 == 16
    const int rest = idx >> 4;                       // b*HH*WW + h*WW + w
    const int h = (rest >> 8) & 255;
    const int b = rest >> 16;

    const float mv = m[rest];
    const float4 hv4 = ((const float4*)hv)[(size_t)(b * HH + h) * (FF / 4) + f4];
    const int4 mx4 = ((const int4*)maxbuf)[b * (FF / 4) + f4];

    float4 o;
    o.x = mv * hv4.x / __int_as_float(mx4.x);
    o.y = mv * hv4.y / __int_as_float(mx4.y);
    o.z = mv * hv4.z / __int_as_float(mx4.z);
    o.w = mv * hv4.w / __int_as_float(mx4.w);
    out[idx] = o;
}

template <int NCH>
static void run_pipeline(const float* lfi, const float* fm, float* out,
                         char* ws, hipStream_t stream) {
    // ws layout: [hv 256KB][maxbuf 4KB][m 1MB][partial BB*NCH*WF*4]
    float* hv = (float*)ws;
    int* mxb = (int*)(ws + (size_t)BB * WW * FF * 4);
    float* m = (float*)(ws + (size_t)BB * WW * FF * 4 + 4096);
    float* partial = (float*)(ws + (size_t)BB * WW * FF * 4 + 4096 +
                              (size_t)BB * HH * WW * 4);

    hipMemsetAsync(mxb, 0, BB * FF * sizeof(int), stream);
    k_stage1<NCH><<<BB * NCH + 1024, 256, 0, stream>>>(fm, lfi, partial, m);
    k_reduce<NCH><<<BB * 16, 256, 0, stream>>>(partial, hv, mxb);
    k_out<<<(BB * HH * WW * FF / 4) / 256, 256, 0, stream>>>(m, hv, mxb,
                                                             (float4*)out);
}

extern "C" void kernel_launch(void* const* d_in, const int* in_sizes, int n_in,
                              void* d_out, int out_size, void* d_ws, size_t ws_size,
                              hipStream_t stream) {
    const float* lfi = (const float*)d_in[0];  // [B,A,H,W,C] f32
    const float* fm  = (const float*)d_in[1];  // [B,H,W,F]   f32
    float* out = (float*)d_out;                // [B,H,W,F]   f32
    char* ws = (char*)d_ws;

    const size_t head = (size_t)BB * WW * FF * 4 + 4096 + (size_t)BB * HH * WW * 4;
    const size_t plane = (size_t)BB * WF * 4;  // per-chunk partial bytes (256KB)

    if (ws_size >= head + 64 * plane) {
        run_pipeline<64>(lfi, fm, out, ws, stream);   // 4 rows/chunk, 16MB partial
    } else if (ws_size >= head + 32 * plane) {
        run_pipeline<32>(lfi, fm, out, ws, stream);   // 8 rows/chunk, 8MB partial
    } else {
        run_pipeline<16>(lfi, fm, out, ws, stream);   // 16 rows/chunk, 4MB partial
    }
}

// Round 4
// 49.444 us; speedup vs baseline: 1.1263x; 1.1263x over previous
//
#include <hip/hip_runtime.h>

// Problem constants (fixed by setup_inputs): lfi [B,A,H,W,C], f_maps [B,H,W,F]
#define BB 4
#define AA 9
#define HH 256
#define WW 256
#define CC 9
#define FF 64
#define WF (WW * FF)   // 16384 floats per h-row of f_maps
#define WF4 (WF / 4)   // 4096 float4 per h-row
#define NHQ 8          // h-eighths for hv partials
#define HQR (HH / NHQ) // 32 rows per chunk

// ---------------------------------------------------------------------------
// k_hv: partial column sums of f_maps over h-eighths.
// Block = (b, hq, wc): 16-w strip, 32 h rows. Thread owns ONE float4 (w,f4)
// cell; per h step the wave loads 1KB contiguous. 8 loads in flight, 1 acc.
// partial[b][hq][w*F+f], each block writes 4KB contiguous.
// ---------------------------------------------------------------------------
__global__ __launch_bounds__(256) void k_hv(const float* __restrict__ fm,
                                            float* __restrict__ partial) {
    const int t = threadIdx.x;
    const int wc = blockIdx.x & 15;
    const int hq = (blockIdx.x >> 4) & (NHQ - 1);
    const int b = blockIdx.x >> 7;  // 16*NHQ == 128 blocks per batch

    const float* base = fm + ((size_t)(b * HH + hq * HQR) * WW + wc * 16) * FF +
                        (t >> 4) * FF + (t & 15) * 4;
    float4 acc = make_float4(0.f, 0.f, 0.f, 0.f);
#pragma unroll 8
    for (int h = 0; h < HQR; ++h) {
        float4 v = *(const float4*)(base + (size_t)h * WW * FF);
        acc.x += v.x; acc.y += v.y; acc.z += v.z; acc.w += v.w;
    }
    ((float4*)partial)[(size_t)(b * NHQ + hq) * WF4 + wc * 256 + t] = acc;
}

// ---------------------------------------------------------------------------
// k_mred (two fused roles, disjoint blocks):
//  blocks [0,512): m partials. Thread owns 4 consecutive hw; per a it loads
//    9 contiguous float4 (wave = 1KB contiguous, 9 in flight) and folds them
//    into 4 accumulators with a static index map. Role 0: a=0..4, role 1:
//    a=5..8 (2x TLP; k_out sums the two partials).
//  blocks [512,576): finalize hv from k_hv's partials (previous dispatch -> 
//    stream-ordered) + per-(b,f) max via LDS + atomicMax.
// ---------------------------------------------------------------------------
__global__ __launch_bounds__(256) void k_mred(const float* __restrict__ lfi,
                                              const float* __restrict__ partial,
                                              float* __restrict__ mpart,
                                              float* __restrict__ hv,
                                              int* __restrict__ mxb) {
    const int t = threadIdx.x;
    if (blockIdx.x < 512) {
        const int role = blockIdx.x >> 8;              // 0 or 1
        const int hw4 = (blockIdx.x & 255) * 256 + t;  // 0..65535
        const int b = hw4 >> 14;                       // 16384 hw4 per batch
        const int hwl = (hw4 & 16383) * 4;             // local hw index
        const size_t astride = (size_t)HH * WW * CC;   // 589824 floats
        const int a0 = role ? 5 : 0;
        const int a1 = role ? 9 : 5;

        const float4* base =
            (const float4*)(lfi + (size_t)b * AA * astride + (size_t)hwl * CC);
        float4 acc = make_float4(0.f, 0.f, 0.f, 0.f);
        for (int a = a0; a < a1; ++a) {
            const float4* p = base + (size_t)a * (astride / 4);
            float4 v0 = p[0], v1 = p[1], v2 = p[2], v3 = p[3], v4 = p[4];
            float4 v5 = p[5], v6 = p[6], v7 = p[7], v8 = p[8];
            // float index 0..35 -> output (idx/9); all compile-time static.
            acc.x += v0.x + v0.y + v0.z + v0.w + v1.x + v1.y + v1.z + v1.w + v2.x;
            acc.y += v2.y + v2.z + v2.w + v3.x + v3.y + v3.z + v3.w + v4.x + v4.y;
            acc.z += v4.z + v4.w + v5.x + v5.y + v5.z + v5.w + v6.x + v6.y + v6.z;
            acc.w += v6.w + v7.x + v7.y + v7.z + v7.w + v8.x + v8.y + v8.z + v8.w;
        }
        ((float4*)mpart)[(size_t)role * 65536 + hw4] = acc;
    } else {
        // ---- hv finalize + max role ----
        const int rb = blockIdx.x - 512;  // 0..63
        const int b = rb >> 4;
        const int i = rb & 15;
        const int wf4 = i * 256 + t;  // 0..4095

        const float4* p4 = (const float4*)partial + (size_t)b * NHQ * WF4 + wf4;
        float4 s = make_float4(0.f, 0.f, 0.f, 0.f);
#pragma unroll
        for (int hq = 0; hq < NHQ; ++hq) {
            float4 v = p4[(size_t)hq * WF4];
            s.x += v.x; s.y += v.y; s.z += v.z; s.w += v.w;
        }
        s.x *= (1.0f / HH); s.y *= (1.0f / HH);
        s.z *= (1.0f / HH); s.w *= (1.0f / HH);
        ((float4*)hv)[(size_t)b * WF4 + wf4] = s;

        // block spans w = i*16 + (t>>4), f = (t&15)*4 .. +3
        __shared__ float lmax[16][FF];
        const int wl = t >> 4, f4 = t & 15;
        lmax[wl][f4 * 4 + 0] = s.x;
        lmax[wl][f4 * 4 + 1] = s.y;
        lmax[wl][f4 * 4 + 2] = s.z;
        lmax[wl][f4 * 4 + 3] = s.w;
        __syncthreads();
        if (t < FF) {
            float mx = lmax[0][t];
#pragma unroll
            for (int j = 1; j < 16; ++j) mx = fmaxf(mx, lmax[j][t]);
            atomicMax(mxb + b * FF + t, __float_as_int(mx));  // positive floats
        }
    }
}

// ---------------------------------------------------------------------------
// k_out: out[b,h,w,f] = m[b,h,w] * hv[b,h,f] / max[b,f]
// m = sum of the two a-range partials * 1/81. v_rcp_f32 for the divide
// (rel err ~1e-7 << 1e-2 threshold). Stores 16B/lane contiguous.
// ---------------------------------------------------------------------------
__global__ __launch_bounds__(256) void k_out(const float* __restrict__ mpart,
                                             const float* __restrict__ hv,
                                             const int* __restrict__ mxb,
                                             float4* __restrict__ out) {
    const int idx = blockIdx.x * 256 + threadIdx.x;  // over B*H*W*F/4
    const int f4 = idx & 15;                         // FF/4 == 16
    const int rest = idx >> 4;                       // b*HH*WW + h*WW + w
    const int h = (rest >> 8) & 255;
    const int b = rest >> 16;

    const float mv =
        (mpart[rest] + mpart[262144 + rest]) * (1.0f / (AA * CC));
    const float4 hv4 = ((const float4*)hv)[(size_t)(b * HH + h) * (FF / 4) + f4];
    const int4 mx4 = ((const int4*)mxb)[b * (FF / 4) + f4];

    float4 o;
    o.x = mv * hv4.x * __builtin_amdgcn_rcpf(__int_as_float(mx4.x));
    o.y = mv * hv4.y * __builtin_amdgcn_rcpf(__int_as_float(mx4.y));
    o.z = mv * hv4.z * __builtin_amdgcn_rcpf(__int_as_float(mx4.z));
    o.w = mv * hv4.w * __builtin_amdgcn_rcpf(__int_as_float(mx4.w));
    out[idx] = o;
}

extern "C" void kernel_launch(void* const* d_in, const int* in_sizes, int n_in,
                              void* d_out, int out_size, void* d_ws, size_t ws_size,
                              hipStream_t stream) {
    const float* lfi = (const float*)d_in[0];  // [B,A,H,W,C] f32
    const float* fm  = (const float*)d_in[1];  // [B,H,W,F]   f32
    float* out = (float*)d_out;                // [B,H,W,F]   f32
    char* ws = (char*)d_ws;

    // ws layout (16B-aligned): hv 256KB | mxb 4KB | mpart 2MB | partial 2MB
    float* hv = (float*)ws;
    int* mxb = (int*)(ws + 262144);
    float* mpart = (float*)(ws + 262144 + 4096);
    float* partial = (float*)(ws + 262144 + 4096 + 2097152);

    hipMemsetAsync(mxb, 0, BB * FF * sizeof(int), stream);
    k_hv<<<BB * NHQ * 16, 256, 0, stream>>>(fm, partial);
    k_mred<<<512 + BB * 16, 256, 0, stream>>>(lfi, partial, mpart, hv, mxb);
    k_out<<<(BB * HH * WW * FF / 4) / 256, 256, 0, stream>>>(mpart, hv, mxb,
                                                             (float4*)out);
}